// Round 6
// baseline (98.173 us; speedup 1.0000x reference)
//
#include <hip/hip_runtime.h>
#include <math.h>

namespace {
constexpr int NV = 3;    // views
constexpr int NC = 16;   // channels
constexpr int ND = 32;   // depths
constexpr int NH = 256;
constexpr int NW = 320;
constexpr int HW = NH * NW;       // 81920
typedef float f32x2 __attribute__((ext_vector_type(2)));
}

// ---------------------------------------------------------------------------
// Setup: proj_v = P_v @ inv(P_0); store rot(9)+trans(3) per src view.
// ---------------------------------------------------------------------------
__global__ void proj_setup_kernel(const float* __restrict__ pm,
                                  float* __restrict__ mats) {
    if (threadIdx.x != 0 || blockIdx.x != 0) return;
    float P[NV][4][4];
    for (int v = 0; v < NV; ++v) {
        const float* E = pm + v * 2 * 16;
        const float* K = pm + v * 2 * 16 + 16;
        for (int i = 0; i < 4; ++i)
            for (int j = 0; j < 4; ++j)
                P[v][i][j] = E[i * 4 + j];
        for (int i = 0; i < 3; ++i)
            for (int j = 0; j < 4; ++j) {
                float acc = 0.f;
                for (int k = 0; k < 3; ++k) acc += K[i * 4 + k] * E[k * 4 + j];
                P[v][i][j] = acc;
            }
    }
    float A[4][8];
    for (int i = 0; i < 4; ++i)
        for (int j = 0; j < 4; ++j) {
            A[i][j] = P[0][i][j];
            A[i][j + 4] = (i == j) ? 1.f : 0.f;
        }
    for (int col = 0; col < 4; ++col) {
        int piv = col;
        float best = fabsf(A[col][col]);
        for (int r = col + 1; r < 4; ++r) {
            float av = fabsf(A[r][col]);
            if (av > best) { best = av; piv = r; }
        }
        if (piv != col)
            for (int j = 0; j < 8; ++j) {
                float t = A[col][j]; A[col][j] = A[piv][j]; A[piv][j] = t;
            }
        float inv = 1.f / A[col][col];
        for (int j = 0; j < 8; ++j) A[col][j] *= inv;
        for (int r = 0; r < 4; ++r) {
            if (r == col) continue;
            float f = A[r][col];
            if (f != 0.f)
                for (int j = 0; j < 8; ++j) A[r][j] -= f * A[col][j];
        }
    }
    float Inv[4][4];
    for (int i = 0; i < 4; ++i)
        for (int j = 0; j < 4; ++j) Inv[i][j] = A[i][j + 4];

    for (int v = 1; v < NV; ++v) {
        float M[4][4];
        for (int i = 0; i < 4; ++i)
            for (int j = 0; j < 4; ++j) {
                float acc = 0.f;
                for (int k = 0; k < 4; ++k) acc += P[v][i][k] * Inv[k][j];
                M[i][j] = acc;
            }
        float* o = mats + (v - 1) * 12;
        for (int i = 0; i < 3; ++i)
            for (int j = 0; j < 3; ++j) o[i * 3 + j] = M[i][j];
        for (int i = 0; i < 3; ++i) o[9 + i] = M[i][3];
    }
}

// ---------------------------------------------------------------------------
// Cost volume R6. One thread per (d, n). [C][HW] layout (lane-coherent
// gathers). Src-view bilinear row-pairs fetched as ONE dwordx2 per
// (row, channel) at xb = clamp(x0, 0, NW-2); border exactness via weight
// swap (when x0 != xb one of the two x-weights is zero). 32 pair-loads per
// view batched before consumption, fenced with sched_barrier(0) so the
// scheduler cannot re-sink them (R5: compiler ignored source-level batching,
// VGPR stayed 40).
// ---------------------------------------------------------------------------
__global__ __launch_bounds__(256, 4) void cost_kernel6(
    const float* __restrict__ feats,   // [V][C][HW]
    const float* __restrict__ dvals,   // [D][HW]
    const float* __restrict__ wreg,    // [C]
    const float* __restrict__ mats,    // [2][12]
    float* __restrict__ cost)          // [D][HW]
{
    const int d = blockIdx.y;
    const unsigned n = blockIdx.x * 256u + threadIdx.x;
    const int y = (int)(n / NW);
    const int x = (int)(n - (unsigned)y * NW);
    const float fx = (float)x, fy = (float)y;
    const unsigned voff = n * 4u;

    const float depth = *(const float*)((const char*)dvals +
                                        (size_t)d * HW * 4 + voff);

    float sum[NC], sq[NC];
#pragma unroll
    for (int c = 0; c < NC; ++c) {
        float r = *(const float*)((const char*)feats + (size_t)c * HW * 4 + voff);
        sum[c] = r;
        sq[c] = r * r;
    }

#pragma unroll
    for (int v = 0; v < 2; ++v) {
        const float* m = mats + v * 12;   // uniform -> scalar loads
        float rx = fmaf(m[0], fx, fmaf(m[1], fy, m[2]));
        float ry = fmaf(m[3], fx, fmaf(m[4], fy, m[5]));
        float rz = fmaf(m[6], fx, fmaf(m[7], fy, m[8]));
        float pxn = fmaf(rx, depth, m[9]);
        float pyn = fmaf(ry, depth, m[10]);
        float z   = fmaf(rz, depth, m[11]);
        z = (fabsf(z) < 1e-6f) ? 1e-6f : z;
        float r0 = __builtin_amdgcn_rcpf(z);
        r0 = r0 * (2.0f - z * r0);          // Newton refine
        float px = pxn * r0, py = pyn * r0;
        float x0f = floorf(px), y0f = floorf(py);
        float wx = px - x0f, wy = py - y0f;
        int x0 = (int)x0f, y0 = (int)y0f;
        int x1 = x0 + 1, y1 = y0 + 1;
        bool vx0 = (x0 >= 0) && (x0 < NW), vx1 = (x1 >= 0) && (x1 < NW);
        bool vy0 = (y0 >= 0) && (y0 < NH), vy1 = (y1 >= 0) && (y1 < NH);
        int cy0 = min(max(y0, 0), NH - 1), cy1 = min(max(y1, 0), NH - 1);
        // x-pair base (contains both corners whenever their weight != 0)
        int xb = min(max(x0, 0), NW - 2);
        bool swapx = (x0 != xb);
        unsigned ob0 = (unsigned)(cy0 * NW + xb) * 4u;   // row y0 pair offset
        unsigned ob1 = (unsigned)(cy1 * NW + xb) * 4u;   // row y1 pair offset
        float w00 = (1.f - wx) * (1.f - wy) * ((vx0 && vy0) ? 1.f : 0.f);
        float w01 = wx * (1.f - wy) * ((vx1 && vy0) ? 1.f : 0.f);
        float w10 = (1.f - wx) * wy * ((vx0 && vy1) ? 1.f : 0.f);
        float w11 = wx * wy * ((vx1 && vy1) ? 1.f : 0.f);
        // weight swap makes clamped-base pair exact at borders
        float wa0 = swapx ? w01 : w00, wb0 = swapx ? w00 : w01;
        float wa1 = swapx ? w11 : w10, wb1 = swapx ? w10 : w11;

        const char* fvb = (const char*)(feats + (size_t)(v + 1) * NC * HW);

        // -------- batched pair-gather phase: 32 dwordx2 in flight ---------
        f32x2 p0[NC], p1[NC];
#pragma unroll
        for (int c = 0; c < NC; ++c) {
            const char* fcb = fvb + (size_t)c * HW * 4;   // uniform SGPR base
            p0[c] = *(const f32x2*)(fcb + ob0);
            p1[c] = *(const f32x2*)(fcb + ob1);
        }
        __builtin_amdgcn_sched_barrier(0);   // keep loads batched (R5 lesson)
        // -------- consume phase ------------------------------------------
#pragma unroll
        for (int c = 0; c < NC; ++c) {
            float val = fmaf(p0[c].x, wa0,
                        fmaf(p0[c].y, wb0,
                        fmaf(p1[c].x, wa1, p1[c].y * wb1)));
            sum[c] += val;
            sq[c] = fmaf(val, val, sq[c]);
        }
    }

    float cst = 0.f;
    const float invV = 1.f / 3.f;
#pragma unroll
    for (int c = 0; c < NC; ++c) {
        float s = sum[c] * invV;
        float var = fmaf(sq[c], invV, -(s * s));
        cst = fmaf(var, wreg[c], cst);
    }
    *(float*)((char*)cost + (size_t)d * HW * 4 + voff) = cst;
}

// ---------------------------------------------------------------------------
// Softmax over D + depth regression + confidence (reads cost from prob
// region of d_out, overwrites with prob).
// ---------------------------------------------------------------------------
__global__ __launch_bounds__(256) void softmax_kernel(
    const float* __restrict__ dvals,
    float* __restrict__ out)
{
    int n = blockIdx.x * blockDim.x + threadIdx.x;
    float* prob = out + 2 * HW;

    float c[ND];
    float mx = -INFINITY;
#pragma unroll
    for (int d = 0; d < ND; ++d) {
        c[d] = prob[d * HW + n];
        mx = fmaxf(mx, c[d]);
    }
    float ssum = 0.f;
#pragma unroll
    for (int d = 0; d < ND; ++d) {
        float e = expf(c[d] - mx);
        c[d] = e;
        ssum += e;
    }
    float inv = 1.f / ssum;
    float depth_acc = 0.f, didx_acc = 0.f;
#pragma unroll
    for (int d = 0; d < ND; ++d) {
        float pv = c[d] * inv;
        c[d] = pv;
        prob[d * HW + n] = pv;
        depth_acc += pv * dvals[d * HW + n];
        didx_acc += pv * (float)d;
    }
    int di = (int)didx_acc;            // trunc toward zero, matches astype(int32)
    di = min(max(di, 0), ND - 1);
    float pdi = 0.f, pdi1 = 0.f;
#pragma unroll
    for (int d = 0; d < ND; ++d) {
        pdi = (d == di) ? c[d] : pdi;
        pdi1 = (d == di + 1) ? c[d] : pdi1;
    }
    out[n] = depth_acc;
    out[HW + n] = pdi + pdi1;
}

extern "C" void kernel_launch(void* const* d_in, const int* in_sizes, int n_in,
                              void* d_out, int out_size, void* d_ws, size_t ws_size,
                              hipStream_t stream) {
    const float* feats = (const float*)d_in[0];
    const float* pm    = (const float*)d_in[1];
    const float* dvals = (const float*)d_in[2];
    const float* wreg  = (const float*)d_in[3];
    float* out = (float*)d_out;
    float* mats = (float*)d_ws;                  // 24 floats

    proj_setup_kernel<<<1, 64, 0, stream>>>(pm, mats);
    cost_kernel6<<<dim3(HW / 256, ND), 256, 0, stream>>>(feats, dvals, wreg,
                                                         mats, out + 2 * HW);
    softmax_kernel<<<HW / 256, 256, 0, stream>>>(dvals, out);
}